// Round 3
// baseline (1385.875 us; speedup 1.0000x reference)
//
#include <hip/hip_runtime.h>

// spatialAttentionScaledGCN — MI355X MFMA version.
// B=8, N=512, T=12, F=32, O=64. All I/O fp32.
// R3: two-pass softmax, barrier-free inner loops.
//   Pass 1 (no barriers): per chunk, score MFMA + wave-local max/sum shuffle
//     reduce; write (max,sum) partial to this wave's LDS column. Chunks are
//     independent -> compiler pipelines the shuffle/exp latency chains.
//   1 barrier. Per-row sequential online combine of 16 wave partials -> MS[512]
//     = (rowmax, inv_f/rowsum). 1 barrier.
//   Pass 2 (no barriers, no shuffles): recompute score MFMA (free at 2% MfmaUtil),
//     w = exp(s*invf - M) * (invf/S) * phase(*adj), pred MFMA accumulate.
//   16 waves/block (1024 thr), each wave owns 2 n-tiles -> 4 waves/SIMD.
//   No atomics, no memsets (exactly-once stores, mask select in epilogue).

#define B_ 8
#define N_ 512
#define T_ 12
#define F_ 32
#define O_ 64
#define NW 16                   // waves per block (1024 threads)

typedef unsigned int uint_t;
typedef unsigned short ushort_t;
typedef _Float16 f16_t;
typedef _Float16 f16x4 __attribute__((ext_vector_type(4)));
typedef _Float16 f16x8 __attribute__((ext_vector_type(8)));
typedef float f32x4 __attribute__((ext_vector_type(4)));

__device__ __forceinline__ int xidx(int b, int n, int t, int f) {
    return ((b * N_ + n) * T_ + t) * F_ + f;
}
// load 8 consecutive fp32, convert to packed f16x8 (one MFMA A/B frag quarter)
__device__ __forceinline__ f16x8 load_frag8(const float* p) {
    float4 a = *reinterpret_cast<const float4*>(p);
    float4 b = *reinterpret_cast<const float4*>(p + 4);
    f16x8 r;
    r[0] = (f16_t)a.x; r[1] = (f16_t)a.y; r[2] = (f16_t)a.z; r[3] = (f16_t)a.w;
    r[4] = (f16_t)b.x; r[5] = (f16_t)b.y; r[6] = (f16_t)b.z; r[7] = (f16_t)b.w;
    return r;
}
union U2H4 { uint2 u; f16x4 h; };

// ---------------------------------------------------------------------------
// Permute one 512x512 fp32 slice into MFMA-lane-order fp16:
// dst halves h = ((mc*32 + nt)*256) + quad*64 + col*4 + j  <=  src[mc*16+quad*4+j][nt*16+col]
// so a consuming lane l=quad*16+col reads its 4 halves with ONE dwordx2.
__global__ __launch_bounds__(256)
void permute_kernel(const float* __restrict__ src, ushort_t* __restrict__ dst)
{
    __shared__ float Lp[16][516];
    const int tid = threadIdx.x;
    const int mc  = blockIdx.x;               // 0..31 row-chunk
    const int s   = blockIdx.y;               // slice (b*12+t for phase; 0 for adj)
    src += (size_t)s * N_ * N_ + (size_t)mc * 16 * N_;
    uint_t* dstu = (uint_t*)dst + (size_t)s * 131072 + (size_t)mc * 4096;

    #pragma unroll
    for (int k = 0; k < 32; ++k) {
        int idx = tid + 256 * k;              // 0..8191
        Lp[idx >> 9][idx & 511] = src[idx];
    }
    __syncthreads();
    #pragma unroll
    for (int k = 0; k < 16; ++k) {
        int u    = tid + 256 * k;             // u32 index 0..4095
        int nt   = u >> 7;
        int r    = u & 127;
        int quad = r >> 5;
        int cl   = (r >> 1) & 15;
        int m0   = quad * 4 + (r & 1) * 2;
        int n    = nt * 16 + cl;
        union { f16_t h[2]; uint_t i; } pk;
        pk.h[0] = (f16_t)Lp[m0][n];
        pk.h[1] = (f16_t)Lp[m0 + 1][n];
        dstu[u] = pk.i;
    }
}

// ---------------------------------------------------------------------------
// One Jacobi iteration step for all (b, t>=1); block = (0, t-1, b), 1024 thr.
// FINAL=1: weight *= adj, Xp = X_t (same t), plain store to agg (no mask).
template <int FINAL>
__global__ __launch_bounds__(1024)
void gcn_kernel(const float* __restrict__ x0,
                const float* __restrict__ xcur,
                float* __restrict__ dst,            // xnext or agg
                const ushort_t* __restrict__ phase_h,
                const ushort_t* __restrict__ adj_h,
                const float* __restrict__ mask)
{
    __shared__ float2 stw[NW][N_];    // per-wave (max,sum) partials, 64 KB
    __shared__ float2 MSl[N_];        // combined (rowmax, inv_f/rowsum), 4 KB

    const int tid  = threadIdx.x;
    const int w    = tid >> 6;
    const int l    = tid & 63;
    const int quad = l >> 4;
    const int col  = l & 15;
    const int t    = FINAL ? blockIdx.y : blockIdx.y + 1;
    const int b    = blockIdx.z;
    const int nt0  = w * 2;                  // wave owns n-tiles nt0, nt0+1
    const float inv_f = 0.17677669529663687f;

    const float* xs     = (FINAL && t == 0) ? x0 : xcur;       // X_t source
    const float* xp_src = FINAL ? xs : ((t == 1) ? x0 : xcur); // pred operand
    const int    tp     = FINAL ? t : t - 1;

    // score B-frags for this wave's 2 n-tiles (fixed across chunks)
    f16x8 bf[2];
    #pragma unroll
    for (int i = 0; i < 2; ++i)
        bf[i] = load_frag8(&xs[xidx(b, (nt0 + i) * 16 + col, t, quad * 8)]);

    const uint_t* phu = (const uint_t*)phase_h + (size_t)(b * T_ + t) * 131072;
    const uint_t* adu = (const uint_t*)adj_h;

    // ================= pass 1: stats, no barriers =================
    #pragma unroll 2
    for (int c = 0; c < 32; ++c) {
        const int mb = c * 16;
        f16x8 af = load_frag8(&xs[xidx(b, mb + col, t, quad * 8)]);

        f32x4 s4[2];
        #pragma unroll
        for (int i = 0; i < 2; ++i)
            s4[i] = __builtin_amdgcn_mfma_f32_16x16x32_f16(
                        af, bf[i], (f32x4){0.f, 0.f, 0.f, 0.f}, 0, 0, 0);

        float mxw[4], sw[4];
        #pragma unroll
        for (int v = 0; v < 4; ++v) {
            s4[0][v] *= inv_f; s4[1][v] *= inv_f;
            mxw[v] = fmaxf(s4[0][v], s4[1][v]);
        }
        #pragma unroll
        for (int d = 1; d < 16; d <<= 1)
            #pragma unroll
            for (int v = 0; v < 4; ++v)
                mxw[v] = fmaxf(mxw[v], __shfl_xor(mxw[v], d, 64));
        #pragma unroll
        for (int v = 0; v < 4; ++v)
            sw[v] = __expf(s4[0][v] - mxw[v]) + __expf(s4[1][v] - mxw[v]);
        #pragma unroll
        for (int d = 1; d < 16; d <<= 1)
            #pragma unroll
            for (int v = 0; v < 4; ++v)
                sw[v] += __shfl_xor(sw[v], d, 64);

        if (col < 4) {
            float mv = (col == 0) ? mxw[0] : (col == 1) ? mxw[1] : (col == 2) ? mxw[2] : mxw[3];
            float sv = (col == 0) ? sw[0]  : (col == 1) ? sw[1]  : (col == 2) ? sw[2]  : sw[3];
            stw[w][mb + quad * 4 + col] = make_float2(mv, sv);
        }
    }

    __syncthreads();
    // ============ combine: one row per thread, sequential online ============
    if (tid < N_) {
        float2 p = stw[0][tid];
        float M = p.x, S = p.y;
        #pragma unroll
        for (int ww = 1; ww < NW; ++ww) {
            p = stw[ww][tid];
            float Mn = fmaxf(M, p.x);
            S = S * __expf(M - Mn) + p.y * __expf(p.x - Mn);
            M = Mn;
        }
        MSl[tid] = make_float2(M, inv_f / S);
    }
    __syncthreads();

    // ================= pass 2: weights + pred MFMA, no barriers =============
    f32x4 acc[2][2];
    #pragma unroll
    for (int i = 0; i < 2; ++i) {
        acc[i][0] = (f32x4){0.f, 0.f, 0.f, 0.f};
        acc[i][1] = (f32x4){0.f, 0.f, 0.f, 0.f};
    }

    #pragma unroll 2
    for (int c = 0; c < 32; ++c) {
        const int mb = c * 16;
        const int mc = c;

        // issue all global loads up front
        f16x8 af = load_frag8(&xs[xidx(b, mb + col, t, quad * 8)]);
        U2H4 ph[2], aj[2];
        #pragma unroll
        for (int i = 0; i < 2; ++i) {
            ph[i].u = *(const uint2*)(phu + (size_t)mc * 4096 + (nt0 + i) * 128 + l * 2);
            if (FINAL)
                aj[i].u = *(const uint2*)(adu + (size_t)mc * 4096 + (nt0 + i) * 128 + l * 2);
        }
        f16x4 bp[2];
        #pragma unroll
        for (int ft = 0; ft < 2; ++ft)
            #pragma unroll
            for (int j = 0; j < 4; ++j)
                bp[ft][j] = (f16_t)xp_src[xidx(b, mb + quad * 4 + j, tp, ft * 16 + col)];

        f32x4 s4[2];
        #pragma unroll
        for (int i = 0; i < 2; ++i)
            s4[i] = __builtin_amdgcn_mfma_f32_16x16x32_f16(
                        af, bf[i], (f32x4){0.f, 0.f, 0.f, 0.f}, 0, 0, 0);

        float2 ms[4];
        #pragma unroll
        for (int v = 0; v < 4; ++v) ms[v] = MSl[mb + quad * 4 + v];

        #pragma unroll
        for (int i = 0; i < 2; ++i) {
            f16x4 wf;
            if (FINAL) {
                #pragma unroll
                for (int v = 0; v < 4; ++v)
                    wf[v] = (f16_t)(__expf(s4[i][v] * inv_f - ms[v].x) * ms[v].y
                                    * (float)ph[i].h[v] * (float)aj[i].h[v]);
            } else {
                #pragma unroll
                for (int v = 0; v < 4; ++v)
                    wf[v] = (f16_t)(__expf(s4[i][v] * inv_f - ms[v].x) * ms[v].y
                                    * (float)ph[i].h[v]);
            }
            #pragma unroll
            for (int ft = 0; ft < 2; ++ft)
                acc[i][ft] = __builtin_amdgcn_mfma_f32_16x16x16f16(wf, bp[ft], acc[i][ft], 0, 0, 0);
        }
    }

    // ---- epilogue: exactly-once plain stores (no atomics, no memset) ----
    #pragma unroll
    for (int i = 0; i < 2; ++i) {
        #pragma unroll
        for (int v = 0; v < 4; ++v) {
            const int n = (nt0 + i) * 16 + quad * 4 + v;
            if (FINAL) {
                float* d0 = &dst[((b * T_ + t) * N_ + n) * F_ + col];
                d0[0]  = acc[i][0][v];
                d0[16] = acc[i][1][v];
            } else {
                const int i0 = xidx(b, n, t, col);
                const float mk  = mask[n];
                const float xc0 = xcur[i0];
                const float xc1 = xcur[i0 + 16];
                dst[i0]      = (mk != 0.f) ? xc0 : acc[i][0][v];
                dst[i0 + 16] = (mk != 0.f) ? xc1 : acc[i][1][v];
            }
        }
    }
}

// out[b,n,t,o] = relu(sum_f agg[b,t,n,f] * theta[f,o])
__global__ __launch_bounds__(256)
void proj_kernel(const float* __restrict__ agg, const float* __restrict__ theta,
                 float* __restrict__ out)
{
    __shared__ float th[F_ * O_];
    int tid = threadIdx.x;
    #pragma unroll
    for (int p = 0; p < 8; ++p) th[tid + 256 * p] = theta[tid + 256 * p];
    __syncthreads();
    int g  = blockIdx.x * 256 + tid;           // ((b*N+n)*T+t)*O+o
    int o  = g & 63;
    int r  = g >> 6;
    int tt = r % T_;
    int r2 = r / T_;
    int n  = r2 & 511;
    int b  = r2 >> 9;
    const float* a = &agg[((b * T_ + tt) * N_ + n) * F_];
    float s = 0.f;
    #pragma unroll
    for (int f = 0; f < F_; ++f) s += a[f] * th[f * O_ + o];
    out[g] = fmaxf(s, 0.f);
}

extern "C" void kernel_launch(void* const* d_in, const int* in_sizes, int n_in,
                              void* d_out, int out_size, void* d_ws, size_t ws_size,
                              hipStream_t stream)
{
    const float* x     = (const float*)d_in[0];
    const float* phase = (const float*)d_in[1];
    const float* adj   = (const float*)d_in[2];
    const float* mask  = (const float*)d_in[3];
    const float* theta = (const float*)d_in[4];
    float* out = (float*)d_out;

    const size_t XE = (size_t)B_ * N_ * T_ * F_;       // 1,572,864 floats
    float*    xA      = (float*)d_ws;                  //  6.3 MB
    float*    xB      = xA + XE;                       //  6.3 MB
    float*    agg     = xB + XE;                       //  6.3 MB
    ushort_t* phase_h = (ushort_t*)(agg + XE);         // 50.3 MB (96 slices, f16 permuted)
    ushort_t* adj_h   = phase_h + (size_t)96 * N_ * N_; // 0.5 MB

    permute_kernel<<<dim3(32, 96), 256, 0, stream>>>(phase, phase_h);
    permute_kernel<<<dim3(32, 1), 256, 0, stream>>>(adj, adj_h);

    const float* cur = x;
    float* bufs[2] = { xA, xB };
    for (int i = 0; i < T_ - 1; ++i) {                 // 11 Jacobi iterations
        float* nxt = bufs[i & 1];
        gcn_kernel<0><<<dim3(1, T_ - 1, B_), 1024, 0, stream>>>(
            x, cur, nxt, phase_h, adj_h, mask);
        cur = nxt;
    }
    gcn_kernel<1><<<dim3(1, T_, B_), 1024, 0, stream>>>(
        x, cur, agg, phase_h, adj_h, mask);
    proj_kernel<<<(B_ * N_ * T_ * O_) / 256, 256, 0, stream>>>(agg, theta, out);
}

// Round 4
// 957.566 us; speedup vs baseline: 1.4473x; 1.4473x over previous
//
#include <hip/hip_runtime.h>

// spatialAttentionScaledGCN — MI355X MFMA version.
// B=8, N=512, T=12, F=32, O=64. All I/O fp32.
// R4: split each Jacobi step into TWO dense-grid, barrier-free kernels.
//   stats_kernel (704 blocks, 4 waves, 0 LDS): per wave, one 16-m tile;
//     transposed score MFMA (A=n-tile,B=m-tile -> m on C cols, exploits
//     score symmetry), online max/sum over all 32 n-tiles in registers,
//     2-stage cross-quad shuffle, write float2 MS[b,t,m]=(M, inv_f/S).
//   pred_kernel (704 blocks, 4 waves, 0 LDS, 0 barriers, 0 shuffles):
//     per wave, one n-tile; loop 32 m-chunks: recompute score MFMA (free
//     at 2% MfmaUtil), w = exp(s*invf - M)*S'*phase(*adj) using preloaded
//     MS, pred MFMA accumulate. Exactly-once stores, mask select epilogue.
// Rationale: R0-R3 showed the single-kernel design is squeezed between
// per-chunk block barriers (serial chain, 88-block starvation) and
// cross-block atomics (fabric RMW). Decoupling stats removes both.

#define B_ 8
#define N_ 512
#define T_ 12
#define F_ 32
#define O_ 64

typedef unsigned int uint_t;
typedef unsigned short ushort_t;
typedef _Float16 f16_t;
typedef _Float16 f16x4 __attribute__((ext_vector_type(4)));
typedef _Float16 f16x8 __attribute__((ext_vector_type(8)));
typedef float f32x4 __attribute__((ext_vector_type(4)));

__device__ __forceinline__ int xidx(int b, int n, int t, int f) {
    return ((b * N_ + n) * T_ + t) * F_ + f;
}
// load 8 consecutive fp32, convert to packed f16x8 (one MFMA A/B frag quarter)
__device__ __forceinline__ f16x8 load_frag8(const float* p) {
    float4 a = *reinterpret_cast<const float4*>(p);
    float4 b = *reinterpret_cast<const float4*>(p + 4);
    f16x8 r;
    r[0] = (f16_t)a.x; r[1] = (f16_t)a.y; r[2] = (f16_t)a.z; r[3] = (f16_t)a.w;
    r[4] = (f16_t)b.x; r[5] = (f16_t)b.y; r[6] = (f16_t)b.z; r[7] = (f16_t)b.w;
    return r;
}
union U2H4 { uint2 u; f16x4 h; };

// ---------------------------------------------------------------------------
// Permute one 512x512 fp32 slice into MFMA-lane-order fp16:
// dst halves h = ((mc*32 + nt)*256) + quad*64 + col*4 + j  <=  src[mc*16+quad*4+j][nt*16+col]
// so a consuming lane l=quad*16+col reads its 4 halves with ONE dwordx2.
__global__ __launch_bounds__(256)
void permute_kernel(const float* __restrict__ src, ushort_t* __restrict__ dst)
{
    __shared__ float Lp[16][516];
    const int tid = threadIdx.x;
    const int mc  = blockIdx.x;               // 0..31 row-chunk
    const int s   = blockIdx.y;               // slice (b*12+t for phase; 0 for adj)
    src += (size_t)s * N_ * N_ + (size_t)mc * 16 * N_;
    uint_t* dstu = (uint_t*)dst + (size_t)s * 131072 + (size_t)mc * 4096;

    #pragma unroll
    for (int k = 0; k < 32; ++k) {
        int idx = tid + 256 * k;              // 0..8191
        Lp[idx >> 9][idx & 511] = src[idx];
    }
    __syncthreads();
    #pragma unroll
    for (int k = 0; k < 16; ++k) {
        int u    = tid + 256 * k;             // u32 index 0..4095
        int nt   = u >> 7;
        int r    = u & 127;
        int quad = r >> 5;
        int cl   = (r >> 1) & 15;
        int m0   = quad * 4 + (r & 1) * 2;
        int n    = nt * 16 + cl;
        union { f16_t h[2]; uint_t i; } pk;
        pk.h[0] = (f16_t)Lp[m0][n];
        pk.h[1] = (f16_t)Lp[m0 + 1][n];
        dstu[u] = pk.i;
    }
}

// ---------------------------------------------------------------------------
// Softmax row stats for all (b,t,m). Block = 256 thr = 4 waves, no LDS.
// Wave owns m-tile mc = blockIdx.x*4 + w. Transposed score MFMA puts the
// wave's 16 m on C-columns; online (M,S) per lane over 32 n-tiles x 4 rows,
// then 2-stage shuffle over quads. MS[m] = (M, inv_f/S).
template <int FINAL>
__global__ __launch_bounds__(256)
void stats_kernel(const float* __restrict__ x0,
                  const float* __restrict__ xcur,
                  float2* __restrict__ MS)
{
    const int tid  = threadIdx.x;
    const int w    = tid >> 6;
    const int l    = tid & 63;
    const int quad = l >> 4;
    const int col  = l & 15;
    const int t    = FINAL ? blockIdx.y : blockIdx.y + 1;
    const int b    = blockIdx.z;
    const int mb   = (blockIdx.x * 4 + w) * 16;
    const float inv_f = 0.17677669529663687f;
    const float* xs = (FINAL && t == 0) ? x0 : xcur;

    f16x8 bm = load_frag8(&xs[xidx(b, mb + col, t, quad * 8)]);   // fixed B-frag

    float M = -1e30f, S = 0.f;
    #pragma unroll 4
    for (int nt = 0; nt < 32; ++nt) {
        f16x8 an = load_frag8(&xs[xidx(b, nt * 16 + col, t, quad * 8)]);
        f32x4 s4 = __builtin_amdgcn_mfma_f32_16x16x32_f16(
                       an, bm, (f32x4){0.f, 0.f, 0.f, 0.f}, 0, 0, 0);
        float m4 = fmaxf(fmaxf(s4[0], s4[1]), fmaxf(s4[2], s4[3])) * inv_f;
        float Mn = fmaxf(M, m4);
        S = S * __expf(M - Mn)
          + (__expf(s4[0] * inv_f - Mn) + __expf(s4[1] * inv_f - Mn))
          + (__expf(s4[2] * inv_f - Mn) + __expf(s4[3] * inv_f - Mn));
        M = Mn;
    }
    #pragma unroll
    for (int d = 16; d < 64; d <<= 1) {
        float Mo = __shfl_xor(M, d, 64), So = __shfl_xor(S, d, 64);
        float Mn = fmaxf(M, Mo);
        S = S * __expf(M - Mn) + So * __expf(Mo - Mn);
        M = Mn;
    }
    if (l < 16)
        MS[(size_t)(b * T_ + t) * N_ + mb + l] = make_float2(M, inv_f / S);
}

// ---------------------------------------------------------------------------
// Pred/agg kernel. Block = 256 thr = 4 waves, no LDS/barriers/shuffles.
// Wave owns n-tile nt = blockIdx.x*4 + w, loops all 32 m-chunks.
// FINAL=1: weight *= adj, Xp = X_t (same t), store to agg (no mask).
template <int FINAL>
__global__ __launch_bounds__(256)
void pred_kernel(const float* __restrict__ x0,
                 const float* __restrict__ xcur,
                 float* __restrict__ dst,            // xnext or agg
                 const ushort_t* __restrict__ phase_h,
                 const ushort_t* __restrict__ adj_h,
                 const float* __restrict__ mask,
                 const float2* __restrict__ MS)
{
    const int tid  = threadIdx.x;
    const int w    = tid >> 6;
    const int l    = tid & 63;
    const int quad = l >> 4;
    const int col  = l & 15;
    const int t    = FINAL ? blockIdx.y : blockIdx.y + 1;
    const int b    = blockIdx.z;
    const int nt   = blockIdx.x * 4 + w;             // wave's n-tile
    const float inv_f = 0.17677669529663687f;

    const float* xs     = (FINAL && t == 0) ? x0 : xcur;       // X_t source
    const float* xp_src = FINAL ? xs : ((t == 1) ? x0 : xcur); // pred operand
    const int    tp     = FINAL ? t : t - 1;

    f16x8 bf = load_frag8(&xs[xidx(b, nt * 16 + col, t, quad * 8)]); // fixed B-frag
    const uint_t* phu = (const uint_t*)phase_h + (size_t)(b * T_ + t) * 131072
                        + nt * 128 + l * 2;
    const uint_t* adu = (const uint_t*)adj_h + nt * 128 + l * 2;
    const float2* msp = MS + (size_t)(b * T_ + t) * N_ + quad * 4;

    f32x4 acc0 = (f32x4){0.f, 0.f, 0.f, 0.f};
    f32x4 acc1 = (f32x4){0.f, 0.f, 0.f, 0.f};

    #pragma unroll 2
    for (int c = 0; c < 32; ++c) {
        const int mb = c * 16;
        // issue all loads up front; chunks independent -> pipelined
        f16x8 af = load_frag8(&xs[xidx(b, mb + col, t, quad * 8)]);
        U2H4 ph; ph.u = *(const uint2*)(phu + (size_t)c * 4096);
        U2H4 aj;
        if (FINAL) aj.u = *(const uint2*)(adu + (size_t)c * 4096);
        float4 msA = *(const float4*)(msp + mb);       // rows mb+quad*4 +0,+1
        float4 msB = *(const float4*)(msp + mb + 2);   // rows +2,+3
        f16x4 bp0, bp1;
        #pragma unroll
        for (int j = 0; j < 4; ++j) {
            bp0[j] = (f16_t)xp_src[xidx(b, mb + quad * 4 + j, tp, col)];
            bp1[j] = (f16_t)xp_src[xidx(b, mb + quad * 4 + j, tp, 16 + col)];
        }

        f32x4 s4 = __builtin_amdgcn_mfma_f32_16x16x32_f16(
                       af, bf, (f32x4){0.f, 0.f, 0.f, 0.f}, 0, 0, 0);

        const float Mv[4] = {msA.x, msA.z, msB.x, msB.z};
        const float Sv[4] = {msA.y, msA.w, msB.y, msB.w};
        f16x4 wf;
        #pragma unroll
        for (int v = 0; v < 4; ++v) {
            float e = __expf(s4[v] * inv_f - Mv[v]) * Sv[v] * (float)ph.h[v];
            if (FINAL) e *= (float)aj.h[v];
            wf[v] = (f16_t)e;
        }
        acc0 = __builtin_amdgcn_mfma_f32_16x16x16f16(wf, bp0, acc0, 0, 0, 0);
        acc1 = __builtin_amdgcn_mfma_f32_16x16x16f16(wf, bp1, acc1, 0, 0, 0);
    }

    // ---- epilogue: exactly-once plain stores ----
    #pragma unroll
    for (int v = 0; v < 4; ++v) {
        const int n = nt * 16 + quad * 4 + v;
        if (FINAL) {
            float* d0 = &dst[((size_t)(b * T_ + t) * N_ + n) * F_ + col];
            d0[0]  = acc0[v];
            d0[16] = acc1[v];
        } else {
            const int i0 = xidx(b, n, t, col);
            const float mk = mask[n];
            dst[i0]      = (mk != 0.f) ? xcur[i0]      : acc0[v];
            dst[i0 + 16] = (mk != 0.f) ? xcur[i0 + 16] : acc1[v];
        }
    }
}

// out[b,n,t,o] = relu(sum_f agg[b,t,n,f] * theta[f,o])
__global__ __launch_bounds__(256)
void proj_kernel(const float* __restrict__ agg, const float* __restrict__ theta,
                 float* __restrict__ out)
{
    __shared__ float th[F_ * O_];
    int tid = threadIdx.x;
    #pragma unroll
    for (int p = 0; p < 8; ++p) th[tid + 256 * p] = theta[tid + 256 * p];
    __syncthreads();
    int g  = blockIdx.x * 256 + tid;           // ((b*N+n)*T+t)*O+o
    int o  = g & 63;
    int r  = g >> 6;
    int tt = r % T_;
    int r2 = r / T_;
    int n  = r2 & 511;
    int b  = r2 >> 9;
    const float* a = &agg[((b * T_ + tt) * N_ + n) * F_];
    float s = 0.f;
    #pragma unroll
    for (int f = 0; f < F_; ++f) s += a[f] * th[f * O_ + o];
    out[g] = fmaxf(s, 0.f);
}

extern "C" void kernel_launch(void* const* d_in, const int* in_sizes, int n_in,
                              void* d_out, int out_size, void* d_ws, size_t ws_size,
                              hipStream_t stream)
{
    const float* x     = (const float*)d_in[0];
    const float* phase = (const float*)d_in[1];
    const float* adj   = (const float*)d_in[2];
    const float* mask  = (const float*)d_in[3];
    const float* theta = (const float*)d_in[4];
    float* out = (float*)d_out;

    const size_t XE = (size_t)B_ * N_ * T_ * F_;       // 1,572,864 floats
    float*    xA      = (float*)d_ws;                  //  6.3 MB
    float*    xB      = xA + XE;                       //  6.3 MB
    float*    agg     = xB + XE;                       //  6.3 MB
    ushort_t* phase_h = (ushort_t*)(agg + XE);         // 50.3 MB (96 slices, f16 permuted)
    ushort_t* adj_h   = phase_h + (size_t)96 * N_ * N_; // 0.5 MB
    float2*   MS      = (float2*)(adj_h + (size_t)N_ * N_); // 0.4 MB stats

    permute_kernel<<<dim3(32, 96), 256, 0, stream>>>(phase, phase_h);
    permute_kernel<<<dim3(32, 1), 256, 0, stream>>>(adj, adj_h);

    const float* cur = x;
    float* bufs[2] = { xA, xB };
    for (int i = 0; i < T_ - 1; ++i) {                 // 11 Jacobi iterations
        float* nxt = bufs[i & 1];
        stats_kernel<0><<<dim3(8, T_ - 1, B_), 256, 0, stream>>>(x, cur, MS);
        pred_kernel<0><<<dim3(8, T_ - 1, B_), 256, 0, stream>>>(
            x, cur, nxt, phase_h, adj_h, mask, MS);
        cur = nxt;
    }
    stats_kernel<1><<<dim3(8, T_, B_), 256, 0, stream>>>(x, cur, MS);
    pred_kernel<1><<<dim3(8, T_, B_), 256, 0, stream>>>(
        x, cur, agg, phase_h, adj_h, mask, MS);
    proj_kernel<<<(B_ * N_ * T_ * O_) / 256, 256, 0, stream>>>(agg, theta, out);
}